// Round 1
// baseline (293.538 us; speedup 1.0000x reference)
//
#include <hip/hip_runtime.h>

typedef __bf16 bf16x8 __attribute__((ext_vector_type(8)));
typedef unsigned short u16x8 __attribute__((ext_vector_type(8)));
typedef float f32x4 __attribute__((ext_vector_type(4)));

constexpr int B_ = 2, L_ = 2048, D_ = 1024, H_ = 16, Dh_ = 64;
constexpr int MROWS = B_ * L_;  // 4096
constexpr float SCALE_Q = 0.125f;  // 64^-0.5

__device__ __forceinline__ unsigned short f2bf(float x) {
  unsigned int u = __float_as_uint(x);
  u += 0x7FFFu + ((u >> 16) & 1u);   // RNE
  return (unsigned short)(u >> 16);
}

// ---------------- prep: hpe = bf16(hs+pe); hid = bf16(hs) ----------------
__global__ __launch_bounds__(256) void k_prep(const float* __restrict__ hs,
                                              const float* __restrict__ pe,
                                              unsigned short* __restrict__ hpe,
                                              unsigned short* __restrict__ hid) {
  int i = blockIdx.x * 256 + threadIdx.x;  // 4 elems per thread
  float4 h = reinterpret_cast<const float4*>(hs)[i];
  float4 p = reinterpret_cast<const float4*>(pe)[i];
  ushort4 a, b;
  a.x = f2bf(h.x + p.x); a.y = f2bf(h.y + p.y); a.z = f2bf(h.z + p.z); a.w = f2bf(h.w + p.w);
  b.x = f2bf(h.x); b.y = f2bf(h.y); b.z = f2bf(h.z); b.w = f2bf(h.w);
  reinterpret_cast<ushort4*>(hpe)[i] = a;
  reinterpret_cast<ushort4*>(hid)[i] = b;
}

// ---------------- weight convert f32 -> bf16 ----------------
__global__ __launch_bounds__(256) void k_conv(const float* __restrict__ w,
                                              unsigned short* __restrict__ o) {
  int i = blockIdx.x * 256 + threadIdx.x;  // 4 elems per thread
  float4 v = reinterpret_cast<const float4*>(w)[i];
  ushort4 r;
  r.x = f2bf(v.x); r.y = f2bf(v.y); r.z = f2bf(v.z); r.w = f2bf(v.w);
  reinterpret_cast<ushort4*>(o)[i] = r;
}

// ---------------- GEMM: C[m,n] = (sum_k A[m,k]*W[n,k] + bias[n]) * scale ----------------
// A: MROWS x 1024 bf16 row-major; W: 1024 x 1024 bf16 row-major ([out,in])
// mode 0: scatter bf16 to (B,H,L,Dh); mode 1: dense f32 (MROWS x D)
__global__ __launch_bounds__(256) void k_gemm(const unsigned short* __restrict__ A,
                                              const unsigned short* __restrict__ W,
                                              const float* __restrict__ bias,
                                              float scale, int mode,
                                              void* __restrict__ out) {
  constexpr int K = 1024;
  __shared__ __align__(16) unsigned short As[128][40];  // +8 pad
  __shared__ __align__(16) unsigned short Ws[128][40];
  const int t = threadIdx.x;
  const int m0 = blockIdx.x * 128, n0 = blockIdx.y * 128;
  const int wave = t >> 6, lane = t & 63, lg = lane >> 4, lr = lane & 15;
  const int wr = wave >> 1, wc = wave & 1;

  f32x4 acc[4][4] = {};

  for (int kt = 0; kt < K / 32; ++kt) {
    const int k0 = kt * 32;
    __syncthreads();
#pragma unroll
    for (int cc = 0; cc < 2; ++cc) {
      int c = t + cc * 256;          // 512 chunks of 16B
      int row = c >> 2, part = c & 3;
      u16x8 va = *reinterpret_cast<const u16x8*>(A + (m0 + row) * K + k0 + part * 8);
      *reinterpret_cast<u16x8*>(&As[row][part * 8]) = va;
      u16x8 vw = *reinterpret_cast<const u16x8*>(W + (n0 + row) * K + k0 + part * 8);
      *reinterpret_cast<u16x8*>(&Ws[row][part * 8]) = vw;
    }
    __syncthreads();

    bf16x8 a[4], b[4];
#pragma unroll
    for (int i = 0; i < 4; ++i) {
      a[i] = *reinterpret_cast<const bf16x8*>(&As[wr * 64 + i * 16 + lr][lg * 8]);
      b[i] = *reinterpret_cast<const bf16x8*>(&Ws[wc * 64 + i * 16 + lr][lg * 8]);
    }
#pragma unroll
    for (int i = 0; i < 4; ++i)
#pragma unroll
      for (int j = 0; j < 4; ++j)
        acc[i][j] = __builtin_amdgcn_mfma_f32_16x16x32_bf16(a[i], b[j], acc[i][j], 0, 0, 0);
  }

  // epilogue: D layout row=(lane>>4)*4+reg, col=lane&15
#pragma unroll
  for (int i = 0; i < 4; ++i) {
#pragma unroll
    for (int j = 0; j < 4; ++j) {
#pragma unroll
      for (int r = 0; r < 4; ++r) {
        int m = m0 + wr * 64 + i * 16 + lg * 4 + r;
        int n = n0 + wc * 64 + j * 16 + lr;
        float v = (acc[i][j][r] + bias[n]) * scale;
        if (mode == 0) {
          int bb = m >> 11, ll = m & 2047, hh = n >> 6, dd = n & 63;
          reinterpret_cast<unsigned short*>(out)[(((long)(bb * H_ + hh) * L_) + ll) * Dh_ + dd] = f2bf(v);
        } else {
          reinterpret_cast<float*>(out)[(long)m * D_ + n] = v;
        }
      }
    }
  }
}

// ---------------- flash attention ----------------
// Q,K,V: (B,H,L,Dh) bf16. attn out: (B,L,D) bf16 merged heads.
__global__ __launch_bounds__(256) void k_attn(const unsigned short* __restrict__ Q,
                                              const unsigned short* __restrict__ Kg,
                                              const unsigned short* __restrict__ Vg,
                                              const float* __restrict__ mask,
                                              unsigned short* __restrict__ attn) {
  __shared__ __align__(16) unsigned short Ks[64][72];
  __shared__ __align__(16) unsigned short Vt[64][72];       // transposed: [d][key]
  __shared__ __align__(16) unsigned short Ps[4][16][72];    // per-wave P tile
  const int t = threadIdx.x;
  const int bx = blockIdx.x;
  const int qt = bx & 31;
  const int h = (bx >> 5) & 15;
  const int bb = bx >> 9;
  const int wave = t >> 6, lane = t & 63, lg = lane >> 4, lr = lane & 15;

  const unsigned short* Qh = Q + (long)(bb * H_ + h) * L_ * Dh_;
  const unsigned short* Kh = Kg + (long)(bb * H_ + h) * L_ * Dh_;
  const unsigned short* Vh = Vg + (long)(bb * H_ + h) * L_ * Dh_;
  const int q0 = qt * 64 + wave * 16;

  // Q fragments (A-frag: row = lane&15, k = (lane>>4)*8 + j)
  bf16x8 aq0 = *reinterpret_cast<const bf16x8*>(Qh + (q0 + lr) * Dh_ + lg * 8);
  bf16x8 aq1 = *reinterpret_cast<const bf16x8*>(Qh + (q0 + lr) * Dh_ + 32 + lg * 8);

  float mrun[4], lrun[4];
  f32x4 acc[4] = {};
#pragma unroll
  for (int r = 0; r < 4; ++r) { mrun[r] = -1e30f; lrun[r] = 0.f; }

  for (int kt = 0; kt < L_ / 64; ++kt) {
    __syncthreads();  // prev PV done before overwriting Ks/Vt
#pragma unroll
    for (int cc = 0; cc < 2; ++cc) {
      int c = t + cc * 256;
      // K: row-major stage (conflict-free b128 writes)
      int krow = c >> 3, kpart = c & 7;
      u16x8 vk = *reinterpret_cast<const u16x8*>(Kh + (kt * 64 + krow) * Dh_ + kpart * 8);
      *reinterpret_cast<u16x8*>(&Ks[krow][kpart * 8]) = vk;
      // V: transpose stage (scalar writes contiguous across lanes)
      int vrow = c & 63, vpart = c >> 6;
      u16x8 vv = *reinterpret_cast<const u16x8*>(Vh + (kt * 64 + vrow) * Dh_ + vpart * 8);
#pragma unroll
      for (int j = 0; j < 8; ++j) Vt[vpart * 8 + j][vrow] = vv[j];
    }
    __syncthreads();

    // S = Q K^T over 4 key-subtiles of 16
    f32x4 s[4];
#pragma unroll
    for (int sub = 0; sub < 4; ++sub) {
      bf16x8 bk0 = *reinterpret_cast<const bf16x8*>(&Ks[sub * 16 + lr][lg * 8]);
      bf16x8 bk1 = *reinterpret_cast<const bf16x8*>(&Ks[sub * 16 + lr][32 + lg * 8]);
      f32x4 sv = {};
      sv = __builtin_amdgcn_mfma_f32_16x16x32_bf16(aq0, bk0, sv, 0, 0, 0);
      sv = __builtin_amdgcn_mfma_f32_16x16x32_bf16(aq1, bk1, sv, 0, 0, 0);
#pragma unroll
      for (int r = 0; r < 4; ++r)
        sv[r] += mask[(long)(q0 + lg * 4 + r) * L_ + (kt * 64 + sub * 16 + lr)];
      s[sub] = sv;
    }

    // online softmax (rows live on reg r, cols across 16 lanes)
    float tmax[4];
#pragma unroll
    for (int r = 0; r < 4; ++r)
      tmax[r] = fmaxf(fmaxf(s[0][r], s[1][r]), fmaxf(s[2][r], s[3][r]));
#pragma unroll
    for (int r = 0; r < 4; ++r) {
      tmax[r] = fmaxf(tmax[r], __shfl_xor(tmax[r], 1));
      tmax[r] = fmaxf(tmax[r], __shfl_xor(tmax[r], 2));
      tmax[r] = fmaxf(tmax[r], __shfl_xor(tmax[r], 4));
      tmax[r] = fmaxf(tmax[r], __shfl_xor(tmax[r], 8));
    }
    float p[4][4], alpha[4], tsum[4];
#pragma unroll
    for (int r = 0; r < 4; ++r) {
      float mn = fmaxf(mrun[r], tmax[r]);
      alpha[r] = __expf(mrun[r] - mn);
      mrun[r] = mn;
      float ps = 0.f;
#pragma unroll
      for (int sub = 0; sub < 4; ++sub) {
        float pv = __expf(s[sub][r] - mn);
        p[sub][r] = pv;
        ps += pv;
      }
      tsum[r] = ps;
    }
#pragma unroll
    for (int r = 0; r < 4; ++r) {
      tsum[r] += __shfl_xor(tsum[r], 1);
      tsum[r] += __shfl_xor(tsum[r], 2);
      tsum[r] += __shfl_xor(tsum[r], 4);
      tsum[r] += __shfl_xor(tsum[r], 8);
      lrun[r] = lrun[r] * alpha[r] + tsum[r];
    }
#pragma unroll
    for (int df = 0; df < 4; ++df)
#pragma unroll
      for (int r = 0; r < 4; ++r) acc[df][r] *= alpha[r];

    // P (D-layout) -> LDS so it can be re-read in A-frag layout
#pragma unroll
    for (int sub = 0; sub < 4; ++sub)
#pragma unroll
      for (int r = 0; r < 4; ++r)
        Ps[wave][lg * 4 + r][sub * 16 + lr] = f2bf(p[sub][r]);
    __syncthreads();

    // PV: acc[q][d] += P(16x64) @ V(64x64)
#pragma unroll
    for (int kf = 0; kf < 2; ++kf) {
      bf16x8 ap = *reinterpret_cast<const bf16x8*>(&Ps[wave][lr][kf * 32 + lg * 8]);
#pragma unroll
      for (int df = 0; df < 4; ++df) {
        bf16x8 bv = *reinterpret_cast<const bf16x8*>(&Vt[df * 16 + lr][kf * 32 + lg * 8]);
        acc[df] = __builtin_amdgcn_mfma_f32_16x16x32_bf16(ap, bv, acc[df], 0, 0, 0);
      }
    }
  }

  // epilogue: normalize, write merged (B,L,D) bf16
#pragma unroll
  for (int df = 0; df < 4; ++df) {
#pragma unroll
    for (int r = 0; r < 4; ++r) {
      int q = q0 + lg * 4 + r;
      float v = acc[df][r] / lrun[r];
      attn[((long)(bb * L_ + q)) * D_ + h * Dh_ + df * 16 + lr] = f2bf(v);
    }
  }
}

extern "C" void kernel_launch(void* const* d_in, const int* in_sizes, int n_in,
                              void* d_out, int out_size, void* d_ws, size_t ws_size,
                              hipStream_t stream) {
  const float* hs   = (const float*)d_in[0];
  const float* pe   = (const float*)d_in[1];
  const float* mask = (const float*)d_in[2];
  const float* Wq   = (const float*)d_in[3];
  const float* bq   = (const float*)d_in[4];
  const float* Wk   = (const float*)d_in[5];
  const float* bk   = (const float*)d_in[6];
  const float* Wv   = (const float*)d_in[7];
  const float* bv   = (const float*)d_in[8];
  const float* Wo   = (const float*)d_in[9];
  const float* bo   = (const float*)d_in[10];

  unsigned short* ws  = (unsigned short*)d_ws;
  unsigned short* hpe = ws;                       // 4096*1024
  unsigned short* hid = hpe + 4096 * 1024;        // 4096*1024
  unsigned short* wqb = hid + 4096 * 1024;        // 1024*1024 each
  unsigned short* wkb = wqb + 1024 * 1024;
  unsigned short* wvb = wkb + 1024 * 1024;
  unsigned short* wob = wvb + 1024 * 1024;
  unsigned short* Qb  = wob + 1024 * 1024;        // 2*16*2048*64 each
  unsigned short* Kb  = Qb + 4194304;
  unsigned short* Vb  = Kb + 4194304;
  unsigned short* Ab  = Vb + 4194304;             // 4096*1024

  k_prep<<<4096, 256, 0, stream>>>(hs, pe, hpe, hid);
  k_conv<<<1024, 256, 0, stream>>>(Wq, wqb);
  k_conv<<<1024, 256, 0, stream>>>(Wk, wkb);
  k_conv<<<1024, 256, 0, stream>>>(Wv, wvb);
  k_conv<<<1024, 256, 0, stream>>>(Wo, wob);

  dim3 g(32, 8);
  k_gemm<<<g, 256, 0, stream>>>(hpe, wqb, bq, SCALE_Q, 0, Qb);
  k_gemm<<<g, 256, 0, stream>>>(hpe, wkb, bk, 1.0f, 0, Kb);
  k_gemm<<<g, 256, 0, stream>>>(hid, wvb, bv, 1.0f, 0, Vb);

  k_attn<<<1024, 256, 0, stream>>>(Qb, Kb, Vb, mask, Ab);

  k_gemm<<<g, 256, 0, stream>>>(Ab, wob, bo, 1.0f, 1, d_out);
}

// Round 2
// 256.695 us; speedup vs baseline: 1.1435x; 1.1435x over previous
//
#include <hip/hip_runtime.h>

typedef __bf16 bf16x8 __attribute__((ext_vector_type(8)));
typedef unsigned short u16x8 __attribute__((ext_vector_type(8)));
typedef float f32x4 __attribute__((ext_vector_type(4)));

constexpr int B_ = 2, L_ = 2048, D_ = 1024, H_ = 16, Dh_ = 64;
constexpr float SCALE_Q = 0.125f;  // 64^-0.5

__device__ __forceinline__ unsigned short f2bf(float x) {
  unsigned int u = __float_as_uint(x);
  u += 0x7FFFu + ((u >> 16) & 1u);   // RNE
  return (unsigned short)(u >> 16);
}

__device__ __forceinline__ void gload16(const void* g, void* l) {
  __builtin_amdgcn_global_load_lds(
      (const __attribute__((address_space(1))) unsigned int*)g,
      (__attribute__((address_space(3))) unsigned int*)l, 16, 0, 0);
}

// ---------------- prep: hpe = bf16(hs+pe); hid = bf16(hs) ----------------
__global__ __launch_bounds__(256) void k_prep(const float* __restrict__ hs,
                                              const float* __restrict__ pe,
                                              unsigned short* __restrict__ hpe,
                                              unsigned short* __restrict__ hid) {
  int i = blockIdx.x * 256 + threadIdx.x;
  float4 h = reinterpret_cast<const float4*>(hs)[i];
  float4 p = reinterpret_cast<const float4*>(pe)[i];
  ushort4 a, b;
  a.x = f2bf(h.x + p.x); a.y = f2bf(h.y + p.y); a.z = f2bf(h.z + p.z); a.w = f2bf(h.w + p.w);
  b.x = f2bf(h.x); b.y = f2bf(h.y); b.z = f2bf(h.z); b.w = f2bf(h.w);
  reinterpret_cast<ushort4*>(hpe)[i] = a;
  reinterpret_cast<ushort4*>(hid)[i] = b;
}

// ---------------- weight convert f32 -> bf16 ----------------
__global__ __launch_bounds__(256) void k_conv(const float* __restrict__ w,
                                              unsigned short* __restrict__ o) {
  int i = blockIdx.x * 256 + threadIdx.x;
  float4 v = reinterpret_cast<const float4*>(w)[i];
  ushort4 r;
  r.x = f2bf(v.x); r.y = f2bf(v.y); r.z = f2bf(v.z); r.w = f2bf(v.w);
  reinterpret_cast<ushort4*>(o)[i] = r;
}

// ---------------- GEMM (m97-style staging): C[m,n]=(sum_k A[m,k]W[n,k]+bias[n])*scale --
__global__ __launch_bounds__(256) void k_gemm(const unsigned short* __restrict__ A,
                                              const unsigned short* __restrict__ W,
                                              const float* __restrict__ bias,
                                              float scale, int mode,
                                              void* __restrict__ out) {
  constexpr int K = 1024;
  __shared__ __align__(16) unsigned short As[128 * 32];
  __shared__ __align__(16) unsigned short Ws[128 * 32];
  const int t = threadIdx.x;
  const int m0 = blockIdx.x * 128, n0 = blockIdx.y * 128;
  const int wave = t >> 6, lane = t & 63, lg = lane >> 4, lr = lane & 15;
  const int wr = wave >> 1, wc = wave & 1;

  // staging chunk geometry: chunk c <-> LDS bytes c*16; row=c>>2 (64B rows),
  // physical slot c&3 holds logical part (c&3)^(row&3)  (XOR swizzle)
  const int c0 = t, c1 = 256 + t;
  const int r0 = c0 >> 2, p0 = (c0 & 3) ^ (r0 & 3);
  const int r1 = c1 >> 2, p1 = (c1 & 3) ^ (r1 & 3);

  f32x4 acc[4][4] = {};

  for (int kt = 0; kt < K / 32; ++kt) {
    const int k0 = kt * 32;
    __syncthreads();
    gload16(A + (m0 + r0) * K + k0 + p0 * 8, (char*)As + wave * 1024);
    gload16(A + (m0 + r1) * K + k0 + p1 * 8, (char*)As + 4096 + wave * 1024);
    gload16(W + (n0 + r0) * K + k0 + p0 * 8, (char*)Ws + wave * 1024);
    gload16(W + (n0 + r1) * K + k0 + p1 * 8, (char*)Ws + 4096 + wave * 1024);
    __syncthreads();

    bf16x8 a[4], b[4];
#pragma unroll
    for (int i = 0; i < 4; ++i) {
      int ra = wr * 64 + i * 16 + lr;
      int rb = wc * 64 + i * 16 + lr;
      a[i] = *reinterpret_cast<const bf16x8*>(As + ra * 32 + ((lg ^ (ra & 3)) * 8));
      b[i] = *reinterpret_cast<const bf16x8*>(Ws + rb * 32 + ((lg ^ (rb & 3)) * 8));
    }
#pragma unroll
    for (int i = 0; i < 4; ++i)
#pragma unroll
      for (int j = 0; j < 4; ++j)
        acc[i][j] = __builtin_amdgcn_mfma_f32_16x16x32_bf16(a[i], b[j], acc[i][j], 0, 0, 0);
  }

  // epilogue: D layout row=(lane>>4)*4+reg, col=lane&15
#pragma unroll
  for (int i = 0; i < 4; ++i) {
#pragma unroll
    for (int j = 0; j < 4; ++j) {
#pragma unroll
      for (int r = 0; r < 4; ++r) {
        int m = m0 + wr * 64 + i * 16 + lg * 4 + r;
        int n = n0 + wc * 64 + j * 16 + lr;
        float v = (acc[i][j][r] + bias[n]) * scale;
        if (mode == 0) {
          int bb = m >> 11, ll = m & 2047, hh = n >> 6, dd = n & 63;
          reinterpret_cast<unsigned short*>(out)[(((long)(bb * H_ + hh) * L_) + ll) * Dh_ + dd] = f2bf(v);
        } else {
          reinterpret_cast<float*>(out)[(long)m * D_ + n] = v;
        }
      }
    }
  }
}

// ---------------- flash attention v2: swapped QK^T, 1 barrier/tile ----------------
__global__ __launch_bounds__(256) void k_attn(const unsigned short* __restrict__ Q,
                                              const unsigned short* __restrict__ Kg,
                                              const unsigned short* __restrict__ Vg,
                                              const float* __restrict__ mask,
                                              unsigned short* __restrict__ attn) {
  __shared__ __align__(16) unsigned short Ks[2][64 * 64];  // [key][d], XOR-swizzled
  __shared__ __align__(16) unsigned short Vt[2][64 * 64];  // [d][key], XOR-swizzled
  __shared__ __align__(16) unsigned short Ps[4][16 * 64];  // per-wave P[q][k], swizzled
  const int t = threadIdx.x;
  const int bx = blockIdx.x;
  const int qt = bx & 31, h = (bx >> 5) & 15, bb = bx >> 9;
  const int wave = t >> 6, lane = t & 63, lg = lane >> 4, lr = lane & 15;
  const int swz = (lr & 7) << 3;  // short-granule XOR for b128 reads

  const unsigned short* Qh = Q + (long)(bb * H_ + h) * L_ * Dh_;
  const unsigned short* Kh = Kg + (long)(bb * H_ + h) * L_ * Dh_;
  const unsigned short* Vh = Vg + (long)(bb * H_ + h) * L_ * Dh_;
  const int q0 = qt * 64 + wave * 16;

  // Q fragments (B-operand: Q[q=lr][d = lg*8+j (+32)])
  bf16x8 bq0 = *reinterpret_cast<const bf16x8*>(Qh + (q0 + lr) * Dh_ + lg * 8);
  bf16x8 bq1 = *reinterpret_cast<const bf16x8*>(Qh + (q0 + lr) * Dh_ + 32 + lg * 8);
  const float* mrow = mask + (long)(q0 + lr) * L_;  // this lane's q row of the mask

  float mrun = -3e38f, lrun = 0.f;
  f32x4 acc[4] = {};

  // K staging geometry: chunk c -> LDS bytes c*16; row=c>>3 (128B rows),
  // physical slot c&7 holds logical part (c&7)^(row&7)
  const int c0 = t, c1 = 256 + t;
  const int kr0 = c0 >> 3, kp0 = (c0 & 7) ^ (kr0 & 7);
  const int kr1 = c1 >> 3, kp1 = (c1 & 7) ^ (kr1 & 7);
  const int vp0 = wave, vp1 = 4 + wave;  // V d-chunk per wave; vrow = lane

  // ---- prologue: stage tile 0 into buf 0 ----
  gload16(Kh + kr0 * Dh_ + kp0 * 8, (char*)&Ks[0][0] + wave * 1024);
  gload16(Kh + kr1 * Dh_ + kp1 * 8, (char*)&Ks[0][0] + 4096 + wave * 1024);
  {
    u16x8 pv0 = *reinterpret_cast<const u16x8*>(Vh + lane * Dh_ + vp0 * 8);
    u16x8 pv1 = *reinterpret_cast<const u16x8*>(Vh + lane * Dh_ + vp1 * 8);
#pragma unroll
    for (int j = 0; j < 8; ++j) {
      Vt[0][(vp0 * 8 + j) * 64 + (lane ^ (j << 3))] = (unsigned short)pv0[j];
      Vt[0][(vp1 * 8 + j) * 64 + (lane ^ (j << 3))] = (unsigned short)pv1[j];
    }
  }
  __syncthreads();

  for (int kt = 0; kt < L_ / 64; ++kt) {
    const int cur = kt & 1;

    // ---- T14 issue-early: next tile's loads in flight under compute ----
    u16x8 nv0, nv1;
    if (kt < 31) {
      const unsigned short* Kt = Kh + (kt + 1) * 64 * Dh_;
      const unsigned short* Vtile = Vh + (kt + 1) * 64 * Dh_;
      gload16(Kt + kr0 * Dh_ + kp0 * 8, (char*)&Ks[cur ^ 1][0] + wave * 1024);
      gload16(Kt + kr1 * Dh_ + kp1 * 8, (char*)&Ks[cur ^ 1][0] + 4096 + wave * 1024);
      nv0 = *reinterpret_cast<const u16x8*>(Vtile + lane * Dh_ + vp0 * 8);
      nv1 = *reinterpret_cast<const u16x8*>(Vtile + lane * Dh_ + vp1 * 8);
    }

    // mask: k = 16*sub + 4*lg + r -> float4 per sub
    float4 mk[4];
#pragma unroll
    for (int sub = 0; sub < 4; ++sub)
      mk[sub] = *reinterpret_cast<const float4*>(mrow + kt * 64 + sub * 16 + lg * 4);

    const unsigned short* Kb = &Ks[cur][0];
    const unsigned short* Vb = &Vt[cur][0];

    // S^T = mfma(K, Q): lane holds S[q=lr][k = kt*64 + 16*sub + 4*lg + r]
    f32x4 s[4];
#pragma unroll
    for (int sub = 0; sub < 4; ++sub) {
      bf16x8 ak0 = *reinterpret_cast<const bf16x8*>(Kb + (sub * 16 + lr) * 64 + ((lg * 8) ^ swz));
      bf16x8 ak1 = *reinterpret_cast<const bf16x8*>(Kb + (sub * 16 + lr) * 64 + ((32 + lg * 8) ^ swz));
      f32x4 sv = {};
      sv = __builtin_amdgcn_mfma_f32_16x16x32_bf16(ak0, bq0, sv, 0, 0, 0);
      sv = __builtin_amdgcn_mfma_f32_16x16x32_bf16(ak1, bq1, sv, 0, 0, 0);
      sv[0] += mk[sub].x; sv[1] += mk[sub].y; sv[2] += mk[sub].z; sv[3] += mk[sub].w;
      s[sub] = sv;
    }

    // online softmax: in-lane reduce (16 vals for one q) + 2 shfl across lg groups
    float tm = s[0][0];
#pragma unroll
    for (int sub = 0; sub < 4; ++sub)
#pragma unroll
      for (int r = 0; r < 4; ++r) tm = fmaxf(tm, s[sub][r]);
    tm = fmaxf(tm, __shfl_xor(tm, 16));
    tm = fmaxf(tm, __shfl_xor(tm, 32));
    float mn = fmaxf(mrun, tm);
    float alpha = __expf(mrun - mn);
    mrun = mn;

    float ts = 0.f;
    unsigned int* PsW = reinterpret_cast<unsigned int*>(&Ps[wave][0]);
#pragma unroll
    for (int sub = 0; sub < 4; ++sub) {
#pragma unroll
      for (int rr = 0; rr < 2; ++rr) {
        float p0 = __expf(s[sub][2 * rr] - mn);
        float p1 = __expf(s[sub][2 * rr + 1] - mn);
        ts += p0 + p1;
        unsigned int pk = ((unsigned int)f2bf(p1) << 16) | (unsigned int)f2bf(p0);
        PsW[lr * 32 + ((8 * sub + 2 * lg + rr) ^ ((lr & 7) << 2))] = pk;
      }
    }
    ts += __shfl_xor(ts, 16);
    ts += __shfl_xor(ts, 32);
    lrun = lrun * alpha + ts;

    // rescale acc: need alpha for q = 4*lg + r (held by lane 20*lg + r)
    float ar[4];
#pragma unroll
    for (int r = 0; r < 4; ++r) ar[r] = __shfl(alpha, 20 * lg + r);
#pragma unroll
    for (int df = 0; df < 4; ++df)
#pragma unroll
      for (int r = 0; r < 4; ++r) acc[df][r] *= ar[r];

    // PV: acc[q][d] += P(16x64) @ V(64x64); P A-frag from per-wave Ps (no barrier)
    const unsigned short* Pw = &Ps[wave][0];
#pragma unroll
    for (int kf = 0; kf < 2; ++kf) {
      bf16x8 ap = *reinterpret_cast<const bf16x8*>(Pw + lr * 64 + ((kf * 32 + lg * 8) ^ swz));
#pragma unroll
      for (int df = 0; df < 4; ++df) {
        bf16x8 bv = *reinterpret_cast<const bf16x8*>(Vb + (df * 16 + lr) * 64 + ((kf * 32 + lg * 8) ^ swz));
        acc[df] = __builtin_amdgcn_mfma_f32_16x16x32_bf16(ap, bv, acc[df], 0, 0, 0);
      }
    }

    // ---- T14 write-late: commit next V tile, then single barrier ----
    if (kt < 31) {
#pragma unroll
      for (int j = 0; j < 8; ++j) {
        Vt[cur ^ 1][(vp0 * 8 + j) * 64 + (lane ^ (j << 3))] = (unsigned short)nv0[j];
        Vt[cur ^ 1][(vp1 * 8 + j) * 64 + (lane ^ (j << 3))] = (unsigned short)nv1[j];
      }
    }
    __syncthreads();
  }

  // epilogue: acc[df][r] = out[q0+4*lg+r][df*16+lr]; l for that q via shfl
  float li[4];
#pragma unroll
  for (int r = 0; r < 4; ++r) li[r] = __shfl(lrun, 20 * lg + r);
#pragma unroll
  for (int df = 0; df < 4; ++df) {
#pragma unroll
    for (int r = 0; r < 4; ++r) {
      int q = q0 + lg * 4 + r;
      float v = acc[df][r] / li[r];
      attn[((long)(bb * L_ + q)) * D_ + h * Dh_ + df * 16 + lr] = f2bf(v);
    }
  }
}

extern "C" void kernel_launch(void* const* d_in, const int* in_sizes, int n_in,
                              void* d_out, int out_size, void* d_ws, size_t ws_size,
                              hipStream_t stream) {
  const float* hs   = (const float*)d_in[0];
  const float* pe   = (const float*)d_in[1];
  const float* mask = (const float*)d_in[2];
  const float* Wq   = (const float*)d_in[3];
  const float* bq   = (const float*)d_in[4];
  const float* Wk   = (const float*)d_in[5];
  const float* bk   = (const float*)d_in[6];
  const float* Wv   = (const float*)d_in[7];
  const float* bv   = (const float*)d_in[8];
  const float* Wo   = (const float*)d_in[9];
  const float* bo   = (const float*)d_in[10];

  unsigned short* ws  = (unsigned short*)d_ws;
  unsigned short* hpe = ws;
  unsigned short* hid = hpe + 4096 * 1024;
  unsigned short* wqb = hid + 4096 * 1024;
  unsigned short* wkb = wqb + 1024 * 1024;
  unsigned short* wvb = wkb + 1024 * 1024;
  unsigned short* wob = wvb + 1024 * 1024;
  unsigned short* Qb  = wob + 1024 * 1024;
  unsigned short* Kb  = Qb + 4194304;
  unsigned short* Vb  = Kb + 4194304;
  unsigned short* Ab  = Vb + 4194304;

  k_prep<<<4096, 256, 0, stream>>>(hs, pe, hpe, hid);
  k_conv<<<1024, 256, 0, stream>>>(Wq, wqb);
  k_conv<<<1024, 256, 0, stream>>>(Wk, wkb);
  k_conv<<<1024, 256, 0, stream>>>(Wv, wvb);
  k_conv<<<1024, 256, 0, stream>>>(Wo, wob);

  dim3 g(32, 8);
  k_gemm<<<g, 256, 0, stream>>>(hpe, wqb, bq, SCALE_Q, 0, Qb);
  k_gemm<<<g, 256, 0, stream>>>(hpe, wkb, bk, 1.0f, 0, Kb);
  k_gemm<<<g, 256, 0, stream>>>(hid, wvb, bv, 1.0f, 0, Vb);

  k_attn<<<1024, 256, 0, stream>>>(Qb, Kb, Vb, mask, Ab);

  k_gemm<<<g, 256, 0, stream>>>(Ab, wob, bo, 1.0f, 1, d_out);
}

// Round 3
// 182.489 us; speedup vs baseline: 1.6085x; 1.4066x over previous
//
#include <hip/hip_runtime.h>

typedef __bf16 bf16x8 __attribute__((ext_vector_type(8)));
typedef unsigned short u16x8 __attribute__((ext_vector_type(8)));
typedef float f32x4 __attribute__((ext_vector_type(4)));
typedef float f32x16 __attribute__((ext_vector_type(16)));

constexpr int B_ = 2, L_ = 2048, D_ = 1024, H_ = 16, Dh_ = 64;
constexpr float LOG2E = 1.44269504088896f;
constexpr float SCALE_Q = 0.125f * LOG2E;   // fold log2e into Q so softmax uses exp2

__device__ __forceinline__ unsigned short f2bf(float x) {
  __bf16 h = (__bf16)x;
  return __builtin_bit_cast(unsigned short, h);
}
__device__ __forceinline__ unsigned int pk2(float lo, float hi) {
  return (unsigned int)f2bf(lo) | ((unsigned int)f2bf(hi) << 16);
}
__device__ __forceinline__ void gload16(const void* g, void* l) {
  __builtin_amdgcn_global_load_lds(
      (const __attribute__((address_space(1))) unsigned int*)g,
      (__attribute__((address_space(3))) unsigned int*)l, 16, 0, 0);
}

// ---------------- fused prep (hpe/hid) + 4 weight converts ----------------
__global__ __launch_bounds__(256) void k_pre(const float* __restrict__ hs,
                                             const float* __restrict__ pe,
                                             const float* __restrict__ Wq,
                                             const float* __restrict__ Wk,
                                             const float* __restrict__ Wv,
                                             const float* __restrict__ Wo,
                                             unsigned short* __restrict__ hpe,
                                             unsigned short* __restrict__ hid,
                                             unsigned short* __restrict__ wq,
                                             unsigned short* __restrict__ wk,
                                             unsigned short* __restrict__ wv,
                                             unsigned short* __restrict__ wo) {
  int b = blockIdx.x, t = threadIdx.x;
  if (b < 4096) {
    int i = b * 256 + t;
    float4 h = reinterpret_cast<const float4*>(hs)[i];
    float4 p = reinterpret_cast<const float4*>(pe)[i];
    ushort4 x, y;
    x.x = f2bf(h.x + p.x); x.y = f2bf(h.y + p.y); x.z = f2bf(h.z + p.z); x.w = f2bf(h.w + p.w);
    y.x = f2bf(h.x); y.y = f2bf(h.y); y.z = f2bf(h.z); y.w = f2bf(h.w);
    reinterpret_cast<ushort4*>(hpe)[i] = x;
    reinterpret_cast<ushort4*>(hid)[i] = y;
  } else {
    int bb = b - 4096;
    int wsel = bb >> 10;
    int i = (bb & 1023) * 256 + t;
    const float* src = wsel == 0 ? Wq : wsel == 1 ? Wk : wsel == 2 ? Wv : Wo;
    unsigned short* dst = wsel == 0 ? wq : wsel == 1 ? wk : wsel == 2 ? wv : wo;
    float4 v = reinterpret_cast<const float4*>(src)[i];
    ushort4 r;
    r.x = f2bf(v.x); r.y = f2bf(v.y); r.z = f2bf(v.z); r.w = f2bf(v.w);
    reinterpret_cast<ushort4*>(dst)[i] = r;
  }
}

// ---------------- GEMM core: dbuf prefetch, 1 barrier per k-step ----------------
template <int MODE>   // 0: scatter bf16 (B,H,L,Dh); 1: dense f32 (M x D)
__device__ __forceinline__ void gemm_core(const unsigned short* __restrict__ A,
                                          const unsigned short* __restrict__ W,
                                          const float* __restrict__ bias,
                                          float scale, void* __restrict__ out) {
  constexpr int K = 1024;
  __shared__ __align__(16) unsigned short As[2][128 * 32];
  __shared__ __align__(16) unsigned short Ws[2][128 * 32];
  const int t = threadIdx.x;
  const int m0 = blockIdx.x * 128, n0 = blockIdx.y * 128;
  const int wave = t >> 6, lane = t & 63, lg = lane >> 4, lr = lane & 15;
  const int wr = wave >> 1, wc = wave & 1;
  const int c0 = t, c1 = 256 + t;
  const int r0 = c0 >> 2, p0 = (c0 & 3) ^ (r0 & 3);
  const int r1 = c1 >> 2, p1 = (c1 & 3) ^ (r1 & 3);

  f32x4 acc[4][4] = {};

  gload16(A + (m0 + r0) * K + p0 * 8, (char*)As[0] + wave * 1024);
  gload16(A + (m0 + r1) * K + p1 * 8, (char*)As[0] + 4096 + wave * 1024);
  gload16(W + (n0 + r0) * K + p0 * 8, (char*)Ws[0] + wave * 1024);
  gload16(W + (n0 + r1) * K + p1 * 8, (char*)Ws[0] + 4096 + wave * 1024);
  __syncthreads();

  for (int kt = 0; kt < K / 32; ++kt) {
    const int cur = kt & 1;
    if (kt < K / 32 - 1) {
      const int k0 = (kt + 1) * 32;
      gload16(A + (m0 + r0) * K + k0 + p0 * 8, (char*)As[cur ^ 1] + wave * 1024);
      gload16(A + (m0 + r1) * K + k0 + p1 * 8, (char*)As[cur ^ 1] + 4096 + wave * 1024);
      gload16(W + (n0 + r0) * K + k0 + p0 * 8, (char*)Ws[cur ^ 1] + wave * 1024);
      gload16(W + (n0 + r1) * K + k0 + p1 * 8, (char*)Ws[cur ^ 1] + 4096 + wave * 1024);
    }
    bf16x8 a[4], b[4];
#pragma unroll
    for (int i = 0; i < 4; ++i) {
      int ra = wr * 64 + i * 16 + lr;
      int rb = wc * 64 + i * 16 + lr;
      a[i] = *reinterpret_cast<const bf16x8*>(As[cur] + ra * 32 + ((lg ^ (ra & 3)) * 8));
      b[i] = *reinterpret_cast<const bf16x8*>(Ws[cur] + rb * 32 + ((lg ^ (rb & 3)) * 8));
    }
#pragma unroll
    for (int i = 0; i < 4; ++i)
#pragma unroll
      for (int j = 0; j < 4; ++j)
        acc[i][j] = __builtin_amdgcn_mfma_f32_16x16x32_bf16(a[i], b[j], acc[i][j], 0, 0, 0);
    __syncthreads();
  }

#pragma unroll
  for (int i = 0; i < 4; ++i) {
#pragma unroll
    for (int j = 0; j < 4; ++j) {
#pragma unroll
      for (int r = 0; r < 4; ++r) {
        int m = m0 + wr * 64 + i * 16 + lg * 4 + r;
        int n = n0 + wc * 64 + j * 16 + lr;
        float v = (acc[i][j][r] + bias[n]) * scale;
        if (MODE == 0) {
          int bb = m >> 11, ll = m & 2047, hh = n >> 6, dd = n & 63;
          reinterpret_cast<unsigned short*>(out)[(((long)(bb * H_ + hh) * L_) + ll) * Dh_ + dd] = f2bf(v);
        } else {
          reinterpret_cast<float*>(out)[(long)m * D_ + n] = v;
        }
      }
    }
  }
}

struct QkvArgs {
  const unsigned short *A0, *A1, *A2, *W0, *W1, *W2;
  const float *b0, *b1, *b2;
  unsigned short *o0, *o1, *o2;
};

__global__ __launch_bounds__(256) void k_qkv(QkvArgs q) {
  int z = blockIdx.z;
  const unsigned short* A = z == 0 ? q.A0 : z == 1 ? q.A1 : q.A2;
  const unsigned short* W = z == 0 ? q.W0 : z == 1 ? q.W1 : q.W2;
  const float* bias = z == 0 ? q.b0 : z == 1 ? q.b1 : q.b2;
  unsigned short* out = z == 0 ? q.o0 : z == 1 ? q.o1 : q.o2;
  float scale = z == 0 ? SCALE_Q : 1.0f;
  gemm_core<0>(A, W, bias, scale, out);
}

__global__ __launch_bounds__(256) void k_outp(const unsigned short* A, const unsigned short* W,
                                              const float* bias, float* out) {
  gemm_core<1>(A, W, bias, 1.0f, out);
}

// ---------------- flash attention v3: 32x32 MFMA, QBLK=32/wave, in-reg P ----------------
__global__ __launch_bounds__(256) void k_attn(const unsigned short* __restrict__ Q,
                                              const unsigned short* __restrict__ Kg,
                                              const unsigned short* __restrict__ Vg,
                                              const float* __restrict__ mask,
                                              unsigned short* __restrict__ attn) {
  __shared__ __align__(16) unsigned short Ks[2][64 * 64];  // [key][d] swizzled
  __shared__ __align__(16) unsigned short Vt[2][64 * 64];  // [d][key] swizzled
  const int t = threadIdx.x;
  const int qt = blockIdx.x;      // 16 q-tiles of 128
  const int bh = blockIdx.y;      // 32 (b,h) pairs; (B,H,L,Dh) head index == bh
  const int h = bh & 15, bb = bh >> 4;
  const int wave = t >> 6, lane = t & 63;
  const int ql = lane & 31, hi = lane >> 5;
  const int q0w = qt * 128 + wave * 32;

  const unsigned short* Qh = Q + (long)bh * L_ * Dh_;
  const unsigned short* Kh = Kg + (long)bh * L_ * Dh_;
  const unsigned short* Vh = Vg + (long)bh * L_ * Dh_;
  const float* mrow = mask + (long)(q0w + ql) * L_;

  // Q B-frags: Q[q0w+ql][c*16 + hi*8 + j]
  bf16x8 bq[4];
#pragma unroll
  for (int c = 0; c < 4; ++c)
    bq[c] = *reinterpret_cast<const bf16x8*>(Qh + (q0w + ql) * Dh_ + c * 16 + hi * 8);

  float mrun = -3e38f, lrun = 0.f;
  f32x16 accO0 = {}, accO1 = {};

  // K staging: chunk c -> LDS bytes c*16; row=c>>3 (128B), phys slot c&7 = logical^(row&7)
  const int c0 = t, c1 = 256 + t;
  const int kr0 = c0 >> 3, kp0 = (c0 & 7) ^ (kr0 & 7);
  const int kr1 = c1 >> 3, kp1 = (c1 & 7) ^ (kr1 & 7);
  const int vp0 = wave, vp1 = 4 + wave;  // V d-chunks; row = lane

  gload16(Kh + kr0 * Dh_ + kp0 * 8, (char*)&Ks[0][0] + wave * 1024);
  gload16(Kh + kr1 * Dh_ + kp1 * 8, (char*)&Ks[0][0] + 4096 + wave * 1024);
  {
    u16x8 pv0 = *reinterpret_cast<const u16x8*>(Vh + lane * Dh_ + vp0 * 8);
    u16x8 pv1 = *reinterpret_cast<const u16x8*>(Vh + lane * Dh_ + vp1 * 8);
#pragma unroll
    for (int j = 0; j < 8; ++j) {
      Vt[0][(vp0 * 8 + j) * 64 + (lane ^ (j << 3))] = (unsigned short)pv0[j];
      Vt[0][(vp1 * 8 + j) * 64 + (lane ^ (j << 3))] = (unsigned short)pv1[j];
    }
  }
  __syncthreads();

  for (int kt = 0; kt < L_ / 64; ++kt) {
    const int cur = kt & 1;

    // issue-early next tile (T14)
    u16x8 nv0, nv1;
    if (kt < 31) {
      const unsigned short* Kt = Kh + (kt + 1) * 64 * Dh_;
      const unsigned short* Vn = Vh + (kt + 1) * 64 * Dh_;
      gload16(Kt + kr0 * Dh_ + kp0 * 8, (char*)&Ks[cur ^ 1][0] + wave * 1024);
      gload16(Kt + kr1 * Dh_ + kp1 * 8, (char*)&Ks[cur ^ 1][0] + 4096 + wave * 1024);
      nv0 = *reinterpret_cast<const u16x8*>(Vn + lane * Dh_ + vp0 * 8);
      nv1 = *reinterpret_cast<const u16x8*>(Vn + lane * Dh_ + vp1 * 8);
    }

    // S^T = K Q^T: lane holds S[q=ql][k = kt*64 + kb*32 + (r&3) + 8*(r>>2) + 4*hi]
    const unsigned short* Kb = &Ks[cur][0];
    f32x16 s0 = {}, s1 = {};
#pragma unroll
    for (int c = 0; c < 4; ++c) {
      int colsw = (c * 16 + hi * 8) ^ ((ql & 7) << 3);
      bf16x8 ak0 = *reinterpret_cast<const bf16x8*>(Kb + ql * 64 + colsw);
      bf16x8 ak1 = *reinterpret_cast<const bf16x8*>(Kb + (32 + ql) * 64 + colsw);
      s0 = __builtin_amdgcn_mfma_f32_32x32x16_bf16(ak0, bq[c], s0, 0, 0, 0);
      s1 = __builtin_amdgcn_mfma_f32_32x32x16_bf16(ak1, bq[c], s1, 0, 0, 0);
    }

    // mask add (in log2 units)
#pragma unroll
    for (int rg = 0; rg < 4; ++rg) {
      float4 mv = *reinterpret_cast<const float4*>(mrow + kt * 64 + rg * 8 + hi * 4);
      s0[4 * rg + 0] = fmaf(mv.x, LOG2E, s0[4 * rg + 0]);
      s0[4 * rg + 1] = fmaf(mv.y, LOG2E, s0[4 * rg + 1]);
      s0[4 * rg + 2] = fmaf(mv.z, LOG2E, s0[4 * rg + 2]);
      s0[4 * rg + 3] = fmaf(mv.w, LOG2E, s0[4 * rg + 3]);
    }
#pragma unroll
    for (int rg = 0; rg < 4; ++rg) {
      float4 mv = *reinterpret_cast<const float4*>(mrow + kt * 64 + 32 + rg * 8 + hi * 4);
      s1[4 * rg + 0] = fmaf(mv.x, LOG2E, s1[4 * rg + 0]);
      s1[4 * rg + 1] = fmaf(mv.y, LOG2E, s1[4 * rg + 1]);
      s1[4 * rg + 2] = fmaf(mv.z, LOG2E, s1[4 * rg + 2]);
      s1[4 * rg + 3] = fmaf(mv.w, LOG2E, s1[4 * rg + 3]);
    }

    // online softmax: row is lane-local (split across hi pair only)
    float tm = s0[0];
#pragma unroll
    for (int r = 1; r < 16; ++r) tm = fmaxf(tm, s0[r]);
#pragma unroll
    for (int r = 0; r < 16; ++r) tm = fmaxf(tm, s1[r]);
    tm = fmaxf(tm, __shfl_xor(tm, 32));

    if (!__all(tm - mrun <= 8.f)) {   // defer-max (T13)
      float mn = fmaxf(mrun, tm);
      float al = __builtin_exp2f(mrun - mn);
      mrun = mn;
      lrun *= al;
#pragma unroll
      for (int r = 0; r < 16; ++r) { accO0[r] *= al; accO1[r] *= al; }
    }

    float ts = 0.f;
    unsigned int w[16];
#pragma unroll
    for (int a = 0; a < 4; ++a) {
      float p0 = __builtin_exp2f(s0[4 * a + 0] - mrun);
      float p1 = __builtin_exp2f(s0[4 * a + 1] - mrun);
      float p2 = __builtin_exp2f(s0[4 * a + 2] - mrun);
      float p3 = __builtin_exp2f(s0[4 * a + 3] - mrun);
      ts += (p0 + p1) + (p2 + p3);
      w[2 * a] = pk2(p0, p1);
      w[2 * a + 1] = pk2(p2, p3);
    }
#pragma unroll
    for (int a = 0; a < 4; ++a) {
      float p0 = __builtin_exp2f(s1[4 * a + 0] - mrun);
      float p1 = __builtin_exp2f(s1[4 * a + 1] - mrun);
      float p2 = __builtin_exp2f(s1[4 * a + 2] - mrun);
      float p3 = __builtin_exp2f(s1[4 * a + 3] - mrun);
      ts += (p0 + p1) + (p2 + p3);
      w[8 + 2 * a] = pk2(p0, p1);
      w[9 + 2 * a] = pk2(p2, p3);
    }
    ts += __shfl_xor(ts, 32);
    lrun += ts;

    // PV: O^T[d][q] += V^T P^T ; P B-frag assembled in-register via 1 shfl per pair
    const unsigned short* Vb = &Vt[cur][0];
#pragma unroll
    for (int kc = 0; kc < 4; ++kc) {
      unsigned int pre0 = hi ? w[4 * kc + 0] : w[4 * kc + 2];
      unsigned int pre1 = hi ? w[4 * kc + 1] : w[4 * kc + 3];
      unsigned int cr0 = __shfl_xor(pre0, 32);
      unsigned int cr1 = __shfl_xor(pre1, 32);
      uint4 bw;
      bw.x = hi ? cr0 : w[4 * kc + 0];
      bw.y = hi ? cr1 : w[4 * kc + 1];
      bw.z = hi ? w[4 * kc + 2] : cr0;
      bw.w = hi ? w[4 * kc + 3] : cr1;
      bf16x8 bp = __builtin_bit_cast(bf16x8, bw);
      int colsw = (kc * 16 + hi * 8) ^ ((ql & 7) << 3);
      bf16x8 av0 = *reinterpret_cast<const bf16x8*>(Vb + ql * 64 + colsw);
      bf16x8 av1 = *reinterpret_cast<const bf16x8*>(Vb + (32 + ql) * 64 + colsw);
      accO0 = __builtin_amdgcn_mfma_f32_32x32x16_bf16(av0, bp, accO0, 0, 0, 0);
      accO1 = __builtin_amdgcn_mfma_f32_32x32x16_bf16(av1, bp, accO1, 0, 0, 0);
    }

    // write-late next V tile, single barrier
    if (kt < 31) {
#pragma unroll
      for (int j = 0; j < 8; ++j) {
        Vt[cur ^ 1][(vp0 * 8 + j) * 64 + (lane ^ (j << 3))] = (unsigned short)nv0[j];
        Vt[cur ^ 1][(vp1 * 8 + j) * 64 + (lane ^ (j << 3))] = (unsigned short)nv1[j];
      }
    }
    __syncthreads();
  }

  // epilogue: O^T reg r -> d = db*32 + (r&3) + 8*(r>>2) + 4*hi, q = ql (lane-local lrun)
  float inv = 1.0f / lrun;
  unsigned short* orow = attn + (long)(bb * L_ + q0w + ql) * D_ + h * Dh_;
#pragma unroll
  for (int rg = 0; rg < 4; ++rg) {
    ushort4 pk;
    pk.x = f2bf(accO0[4 * rg + 0] * inv);
    pk.y = f2bf(accO0[4 * rg + 1] * inv);
    pk.z = f2bf(accO0[4 * rg + 2] * inv);
    pk.w = f2bf(accO0[4 * rg + 3] * inv);
    *reinterpret_cast<ushort4*>(orow + rg * 8 + hi * 4) = pk;
  }
#pragma unroll
  for (int rg = 0; rg < 4; ++rg) {
    ushort4 pk;
    pk.x = f2bf(accO1[4 * rg + 0] * inv);
    pk.y = f2bf(accO1[4 * rg + 1] * inv);
    pk.z = f2bf(accO1[4 * rg + 2] * inv);
    pk.w = f2bf(accO1[4 * rg + 3] * inv);
    *reinterpret_cast<ushort4*>(orow + 32 + rg * 8 + hi * 4) = pk;
  }
}

extern "C" void kernel_launch(void* const* d_in, const int* in_sizes, int n_in,
                              void* d_out, int out_size, void* d_ws, size_t ws_size,
                              hipStream_t stream) {
  const float* hs   = (const float*)d_in[0];
  const float* pe   = (const float*)d_in[1];
  const float* mask = (const float*)d_in[2];
  const float* Wq   = (const float*)d_in[3];
  const float* bq   = (const float*)d_in[4];
  const float* Wk   = (const float*)d_in[5];
  const float* bk   = (const float*)d_in[6];
  const float* Wv   = (const float*)d_in[7];
  const float* bv   = (const float*)d_in[8];
  const float* Wo   = (const float*)d_in[9];
  const float* bo   = (const float*)d_in[10];

  unsigned short* ws  = (unsigned short*)d_ws;
  unsigned short* hpe = ws;
  unsigned short* hid = hpe + 4096 * 1024;
  unsigned short* wqb = hid + 4096 * 1024;
  unsigned short* wkb = wqb + 1024 * 1024;
  unsigned short* wvb = wkb + 1024 * 1024;
  unsigned short* wob = wvb + 1024 * 1024;
  unsigned short* Qb  = wob + 1024 * 1024;
  unsigned short* Kb  = Qb + 4194304;
  unsigned short* Vb  = Kb + 4194304;
  unsigned short* Ab  = Vb + 4194304;

  k_pre<<<8192, 256, 0, stream>>>(hs, pe, Wq, Wk, Wv, Wo, hpe, hid, wqb, wkb, wvb, wob);

  QkvArgs qa{hpe, hpe, hid, wqb, wkb, wvb, bq, bk, bv, Qb, Kb, Vb};
  k_qkv<<<dim3(32, 8, 3), 256, 0, stream>>>(qa);

  k_attn<<<dim3(16, 32), 256, 0, stream>>>(Qb, Kb, Vb, mask, Ab);

  k_outp<<<dim3(32, 8), 256, 0, stream>>>(Ab, wob, bo, (float*)d_out);
}

// Round 4
// 168.666 us; speedup vs baseline: 1.7403x; 1.0820x over previous
//
#include <hip/hip_runtime.h>

typedef __bf16 bf16x8 __attribute__((ext_vector_type(8)));
typedef unsigned short u16x8 __attribute__((ext_vector_type(8)));
typedef float f32x4 __attribute__((ext_vector_type(4)));
typedef float f32x16 __attribute__((ext_vector_type(16)));

constexpr int B_ = 2, L_ = 2048, D_ = 1024, H_ = 16, Dh_ = 64;
constexpr float LOG2E = 1.44269504088896f;
constexpr float SCALE_Q = 0.125f * LOG2E;   // fold log2e into Q so softmax uses exp2

__device__ __forceinline__ unsigned short f2bf(float x) {
  __bf16 h = (__bf16)x;
  return __builtin_bit_cast(unsigned short, h);
}
__device__ __forceinline__ unsigned int cvtpk(float lo, float hi) {
  unsigned int r;
  asm("v_cvt_pk_bf16_f32 %0, %1, %2" : "=v"(r) : "v"(lo), "v"(hi));
  return r;
}
__device__ __forceinline__ void gload16(const void* g, void* l) {
  __builtin_amdgcn_global_load_lds(
      (const __attribute__((address_space(1))) unsigned int*)g,
      (__attribute__((address_space(3))) unsigned int*)l, 16, 0, 0);
}

// ------- fused prep (hpe/hid) + 4 weight converts + mask-zero tile flags -------
__global__ __launch_bounds__(256) void k_pre(const float* __restrict__ hs,
                                             const float* __restrict__ pe,
                                             const float* __restrict__ Wq,
                                             const float* __restrict__ Wk,
                                             const float* __restrict__ Wv,
                                             const float* __restrict__ Wo,
                                             const float* __restrict__ mask,
                                             unsigned short* __restrict__ hpe,
                                             unsigned short* __restrict__ hid,
                                             unsigned short* __restrict__ wq,
                                             unsigned short* __restrict__ wk,
                                             unsigned short* __restrict__ wv,
                                             unsigned short* __restrict__ wo,
                                             unsigned char* __restrict__ mflag) {
  int b = blockIdx.x, t = threadIdx.x;
  if (b < 4096) {
    int i = b * 256 + t;
    float4 h = reinterpret_cast<const float4*>(hs)[i];
    float4 p = reinterpret_cast<const float4*>(pe)[i];
    ushort4 x, y;
    x.x = f2bf(h.x + p.x); x.y = f2bf(h.y + p.y); x.z = f2bf(h.z + p.z); x.w = f2bf(h.w + p.w);
    y.x = f2bf(h.x); y.y = f2bf(h.y); y.z = f2bf(h.z); y.w = f2bf(h.w);
    reinterpret_cast<ushort4*>(hpe)[i] = x;
    reinterpret_cast<ushort4*>(hid)[i] = y;
  } else if (b < 8192) {
    int bb = b - 4096;
    int wsel = bb >> 10;
    int i = (bb & 1023) * 256 + t;
    const float* src = wsel == 0 ? Wq : wsel == 1 ? Wk : wsel == 2 ? Wv : Wo;
    unsigned short* dst = wsel == 0 ? wq : wsel == 1 ? wk : wsel == 2 ? wv : wo;
    float4 v = reinterpret_cast<const float4*>(src)[i];
    ushort4 r;
    r.x = f2bf(v.x); r.y = f2bf(v.y); r.z = f2bf(v.z); r.w = f2bf(v.w);
    reinterpret_cast<ushort4*>(dst)[i] = r;
  } else {
    // flag region rg: 32 q-rows x 64 k-cols of the mask -> 1 byte (nonzero anywhere?)
    int rg = b - 8192;                 // 0..2047
    int qt = rg >> 5, kt = rg & 31;
    int row = qt * 32 + (t >> 3);
    int col = kt * 64 + (t & 7) * 8;
    const float* mp = mask + (long)row * L_ + col;
    float4 a = *reinterpret_cast<const float4*>(mp);
    float4 c = *reinterpret_cast<const float4*>(mp + 4);
    bool nz = (a.x != 0.f) | (a.y != 0.f) | (a.z != 0.f) | (a.w != 0.f) |
              (c.x != 0.f) | (c.y != 0.f) | (c.z != 0.f) | (c.w != 0.f);
    __shared__ unsigned int sf[4];
    unsigned long long wb = __ballot(nz);
    int wave = t >> 6, lane = t & 63;
    if (lane == 0) sf[wave] = (wb != 0ULL);
    __syncthreads();
    if (t == 0) mflag[rg] = (sf[0] | sf[1] | sf[2] | sf[3]) ? 1 : 0;
  }
}

// ---------------- GEMM core: dbuf prefetch, 1 barrier per k-step ----------------
// MODE 0: scatter bf16 (B,H,L,Dh); MODE 1: dense f32 (M x D); MODE 2: V^T bf16 [BH][Dh][L]
template <int MODE>
__device__ __forceinline__ void gemm_core(const unsigned short* __restrict__ A,
                                          const unsigned short* __restrict__ W,
                                          const float* __restrict__ bias,
                                          float scale, void* __restrict__ out) {
  constexpr int K = 1024;
  __shared__ __align__(16) unsigned short As[2][128 * 32];
  __shared__ __align__(16) unsigned short Ws[2][128 * 32];
  const int t = threadIdx.x;
  const int m0 = blockIdx.x * 128, n0 = blockIdx.y * 128;
  const int wave = t >> 6, lane = t & 63, lg = lane >> 4, lr = lane & 15;
  const int wr = wave >> 1, wc = wave & 1;
  const int c0 = t, c1 = 256 + t;
  const int r0 = c0 >> 2, p0 = (c0 & 3) ^ (r0 & 3);
  const int r1 = c1 >> 2, p1 = (c1 & 3) ^ (r1 & 3);

  f32x4 acc[4][4] = {};

  gload16(A + (m0 + r0) * K + p0 * 8, (char*)As[0] + wave * 1024);
  gload16(A + (m0 + r1) * K + p1 * 8, (char*)As[0] + 4096 + wave * 1024);
  gload16(W + (n0 + r0) * K + p0 * 8, (char*)Ws[0] + wave * 1024);
  gload16(W + (n0 + r1) * K + p1 * 8, (char*)Ws[0] + 4096 + wave * 1024);
  __syncthreads();

  for (int kt = 0; kt < K / 32; ++kt) {
    const int cur = kt & 1;
    if (kt < K / 32 - 1) {
      const int k0 = (kt + 1) * 32;
      gload16(A + (m0 + r0) * K + k0 + p0 * 8, (char*)As[cur ^ 1] + wave * 1024);
      gload16(A + (m0 + r1) * K + k0 + p1 * 8, (char*)As[cur ^ 1] + 4096 + wave * 1024);
      gload16(W + (n0 + r0) * K + k0 + p0 * 8, (char*)Ws[cur ^ 1] + wave * 1024);
      gload16(W + (n0 + r1) * K + k0 + p1 * 8, (char*)Ws[cur ^ 1] + 4096 + wave * 1024);
    }
    bf16x8 a[4], b[4];
#pragma unroll
    for (int i = 0; i < 4; ++i) {
      int ra = wr * 64 + i * 16 + lr;
      int rb = wc * 64 + i * 16 + lr;
      a[i] = *reinterpret_cast<const bf16x8*>(As[cur] + ra * 32 + ((lg ^ (ra & 3)) * 8));
      b[i] = *reinterpret_cast<const bf16x8*>(Ws[cur] + rb * 32 + ((lg ^ (rb & 3)) * 8));
    }
#pragma unroll
    for (int i = 0; i < 4; ++i)
#pragma unroll
      for (int j = 0; j < 4; ++j)
        acc[i][j] = __builtin_amdgcn_mfma_f32_16x16x32_bf16(a[i], b[j], acc[i][j], 0, 0, 0);
    __syncthreads();
  }

#pragma unroll
  for (int i = 0; i < 4; ++i) {
#pragma unroll
    for (int j = 0; j < 4; ++j) {
      int n = n0 + wc * 64 + j * 16 + lr;
      if (MODE == 2) {
        // V^T: regs r=0..3 are consecutive l -> ushort4 store at [bh][d][l]
        int l0 = m0 + wr * 64 + i * 16 + lg * 4;
        int bb = l0 >> 11, l = l0 & 2047, hh = n >> 6, dd = n & 63;
        float bn = bias[n];
        ushort4 pk;
        pk.x = f2bf(acc[i][j][0] + bn);
        pk.y = f2bf(acc[i][j][1] + bn);
        pk.z = f2bf(acc[i][j][2] + bn);
        pk.w = f2bf(acc[i][j][3] + bn);
        *reinterpret_cast<ushort4*>(reinterpret_cast<unsigned short*>(out) +
            (((long)(bb * H_ + hh) * Dh_ + dd) * L_ + l)) = pk;
      } else {
#pragma unroll
        for (int r = 0; r < 4; ++r) {
          int m = m0 + wr * 64 + i * 16 + lg * 4 + r;
          float v = (acc[i][j][r] + bias[n]) * scale;
          if (MODE == 0) {
            int bb = m >> 11, ll = m & 2047, hh = n >> 6, dd = n & 63;
            reinterpret_cast<unsigned short*>(out)[(((long)(bb * H_ + hh) * L_) + ll) * Dh_ + dd] = f2bf(v);
          } else {
            reinterpret_cast<float*>(out)[(long)m * D_ + n] = v;
          }
        }
      }
    }
  }
}

struct QkvArgs {
  const unsigned short *A0, *A1, *A2, *W0, *W1, *W2;
  const float *b0, *b1, *b2;
  unsigned short *o0, *o1, *o2;
};

__global__ __launch_bounds__(256) void k_qkv(QkvArgs q) {
  int z = blockIdx.z;
  if (z == 2) {
    gemm_core<2>(q.A2, q.W2, q.b2, 1.0f, q.o2);
  } else {
    const unsigned short* A = z == 0 ? q.A0 : q.A1;
    const unsigned short* W = z == 0 ? q.W0 : q.W1;
    const float* bias = z == 0 ? q.b0 : q.b1;
    unsigned short* out = z == 0 ? q.o0 : q.o1;
    gemm_core<0>(A, W, bias, z == 0 ? SCALE_Q : 1.0f, out);
  }
}

__global__ __launch_bounds__(256) void k_outp(const unsigned short* A, const unsigned short* W,
                                              const float* bias, float* out) {
  gemm_core<1>(A, W, bias, 1.0f, out);
}

// -------- flash attention v4: V^T pre-staged, mask flags, cvt_pk packing --------
__global__ __launch_bounds__(256) void k_attn(const unsigned short* __restrict__ Q,
                                              const unsigned short* __restrict__ Kg,
                                              const unsigned short* __restrict__ Vtg,
                                              const float* __restrict__ mask,
                                              const unsigned char* __restrict__ mflag,
                                              unsigned short* __restrict__ attn) {
  __shared__ __align__(16) unsigned short Ks[2][64 * 64];  // [key][d] swizzled
  __shared__ __align__(16) unsigned short Vs[2][64 * 64];  // [d][key] swizzled
  const int t = threadIdx.x;
  const int qt = blockIdx.x;      // 16 q-tiles of 128
  const int bh = blockIdx.y;      // 32 (b,h) pairs
  const int h = bh & 15, bb = bh >> 4;
  const int wave = t >> 6, lane = t & 63;
  const int ql = lane & 31, hi = lane >> 5;
  const int q0w = qt * 128 + wave * 32;

  const unsigned short* Qh = Q + (long)bh * L_ * Dh_;
  const unsigned short* Kh = Kg + (long)bh * L_ * Dh_;
  const unsigned short* Vh = Vtg + (long)bh * Dh_ * L_;   // V^T: [d][L]
  const float* mrow = mask + (long)(q0w + ql) * L_;

  // Q B-frags
  bf16x8 bq[4];
#pragma unroll
  for (int c = 0; c < 4; ++c)
    bq[c] = *reinterpret_cast<const bf16x8*>(Qh + (q0w + ql) * Dh_ + c * 16 + hi * 8);

  // mask flags for this wave's 32 q-rows -> one 32-bit scalar mask over kv tiles
  unsigned char mb = mflag[(q0w >> 5) * 32 + (lane & 31)];
  unsigned long long mbits = __ballot((lane < 32) && (mb != 0));

  float mrun = -3e38f, lrun = 0.f;
  f32x16 accO0 = {}, accO1 = {};

  // staging: chunk c -> LDS bytes c*16; row=c>>3, phys slot c&7 = logical^(row&7)
  const int c0 = t, c1 = 256 + t;
  const int r0 = c0 >> 3, s0g = (c0 & 7) ^ (r0 & 7);
  const int r1 = c1 >> 3, s1g = (c1 & 7) ^ (r1 & 7);

  gload16(Kh + r0 * Dh_ + s0g * 8, (char*)&Ks[0][0] + wave * 1024);
  gload16(Kh + r1 * Dh_ + s1g * 8, (char*)&Ks[0][0] + 4096 + wave * 1024);
  gload16(Vh + r0 * L_ + s0g * 8, (char*)&Vs[0][0] + wave * 1024);
  gload16(Vh + r1 * L_ + s1g * 8, (char*)&Vs[0][0] + 4096 + wave * 1024);
  __syncthreads();

  for (int kt = 0; kt < L_ / 64; ++kt) {
    const int cur = kt & 1;

    if (kt < 31) {
      const unsigned short* Kt = Kh + (kt + 1) * 64 * Dh_;
      const unsigned short* Vn = Vh + (kt + 1) * 64;
      gload16(Kt + r0 * Dh_ + s0g * 8, (char*)&Ks[cur ^ 1][0] + wave * 1024);
      gload16(Kt + r1 * Dh_ + s1g * 8, (char*)&Ks[cur ^ 1][0] + 4096 + wave * 1024);
      gload16(Vn + r0 * L_ + s0g * 8, (char*)&Vs[cur ^ 1][0] + wave * 1024);
      gload16(Vn + r1 * L_ + s1g * 8, (char*)&Vs[cur ^ 1][0] + 4096 + wave * 1024);
    }

    // S^T = K Q^T: lane holds S[q=ql][k = kt*64 + kb*32 + (r&3) + 8*(r>>2) + 4*hi]
    const unsigned short* Kb = &Ks[cur][0];
    f32x16 s0 = {}, s1 = {};
#pragma unroll
    for (int c = 0; c < 4; ++c) {
      int colsw = (c * 16 + hi * 8) ^ ((ql & 7) << 3);
      bf16x8 ak0 = *reinterpret_cast<const bf16x8*>(Kb + ql * 64 + colsw);
      bf16x8 ak1 = *reinterpret_cast<const bf16x8*>(Kb + (32 + ql) * 64 + colsw);
      s0 = __builtin_amdgcn_mfma_f32_32x32x16_bf16(ak0, bq[c], s0, 0, 0, 0);
      s1 = __builtin_amdgcn_mfma_f32_32x32x16_bf16(ak1, bq[c], s1, 0, 0, 0);
    }

    if ((mbits >> kt) & 1ULL) {   // mask add (log2 units) only when tile has nonzeros
#pragma unroll
      for (int rg = 0; rg < 4; ++rg) {
        float4 mv = *reinterpret_cast<const float4*>(mrow + kt * 64 + rg * 8 + hi * 4);
        s0[4 * rg + 0] = fmaf(mv.x, LOG2E, s0[4 * rg + 0]);
        s0[4 * rg + 1] = fmaf(mv.y, LOG2E, s0[4 * rg + 1]);
        s0[4 * rg + 2] = fmaf(mv.z, LOG2E, s0[4 * rg + 2]);
        s0[4 * rg + 3] = fmaf(mv.w, LOG2E, s0[4 * rg + 3]);
      }
#pragma unroll
      for (int rg = 0; rg < 4; ++rg) {
        float4 mv = *reinterpret_cast<const float4*>(mrow + kt * 64 + 32 + rg * 8 + hi * 4);
        s1[4 * rg + 0] = fmaf(mv.x, LOG2E, s1[4 * rg + 0]);
        s1[4 * rg + 1] = fmaf(mv.y, LOG2E, s1[4 * rg + 1]);
        s1[4 * rg + 2] = fmaf(mv.z, LOG2E, s1[4 * rg + 2]);
        s1[4 * rg + 3] = fmaf(mv.w, LOG2E, s1[4 * rg + 3]);
      }
    }

    // online softmax: row lane-local (split across hi pair only)
    float tm = s0[0];
#pragma unroll
    for (int r = 1; r < 16; ++r) tm = fmaxf(tm, s0[r]);
#pragma unroll
    for (int r = 0; r < 16; ++r) tm = fmaxf(tm, s1[r]);
    tm = fmaxf(tm, __shfl_xor(tm, 32));

    if (!__all(tm - mrun <= 8.f)) {   // defer-max (T13)
      float mn = fmaxf(mrun, tm);
      float al = __builtin_exp2f(mrun - mn);
      mrun = mn;
      lrun *= al;
#pragma unroll
      for (int r = 0; r < 16; ++r) { accO0[r] *= al; accO1[r] *= al; }
    }

    float ts = 0.f;
    unsigned int w[16];
#pragma unroll
    for (int a = 0; a < 4; ++a) {
      float p0 = __builtin_exp2f(s0[4 * a + 0] - mrun);
      float p1 = __builtin_exp2f(s0[4 * a + 1] - mrun);
      float p2 = __builtin_exp2f(s0[4 * a + 2] - mrun);
      float p3 = __builtin_exp2f(s0[4 * a + 3] - mrun);
      ts += (p0 + p1) + (p2 + p3);
      w[2 * a] = cvtpk(p0, p1);
      w[2 * a + 1] = cvtpk(p2, p3);
    }
#pragma unroll
    for (int a = 0; a < 4; ++a) {
      float p0 = __builtin_exp2f(s1[4 * a + 0] - mrun);
      float p1 = __builtin_exp2f(s1[4 * a + 1] - mrun);
      float p2 = __builtin_exp2f(s1[4 * a + 2] - mrun);
      float p3 = __builtin_exp2f(s1[4 * a + 3] - mrun);
      ts += (p0 + p1) + (p2 + p3);
      w[8 + 2 * a] = cvtpk(p0, p1);
      w[9 + 2 * a] = cvtpk(p2, p3);
    }
    ts += __shfl_xor(ts, 32);
    lrun += ts;

    // PV: O^T[d][q] += V^T P^T ; P B-frag assembled via 1 shfl per pair
    const unsigned short* Vb = &Vs[cur][0];
#pragma unroll
    for (int kc = 0; kc < 4; ++kc) {
      unsigned int pre0 = hi ? w[4 * kc + 0] : w[4 * kc + 2];
      unsigned int pre1 = hi ? w[4 * kc + 1] : w[4 * kc + 3];
      unsigned int cr0 = __shfl_xor(pre0, 32);
      unsigned int cr1 = __shfl_xor(pre1, 32);
      uint4 bw;
      bw.x = hi ? cr0 : w[4 * kc + 0];
      bw.y = hi ? cr1 : w[4 * kc + 1];
      bw.z = hi ? w[4 * kc + 2] : cr0;
      bw.w = hi ? w[4 * kc + 3] : cr1;
      bf16x8 bp = __builtin_bit_cast(bf16x8, bw);
      int colsw = (kc * 16 + hi * 8) ^ ((ql & 7) << 3);
      bf16x8 av0 = *reinterpret_cast<const bf16x8*>(Vb + ql * 64 + colsw);
      bf16x8 av1 = *reinterpret_cast<const bf16x8*>(Vb + (32 + ql) * 64 + colsw);
      accO0 = __builtin_amdgcn_mfma_f32_32x32x16_bf16(av0, bp, accO0, 0, 0, 0);
      accO1 = __builtin_amdgcn_mfma_f32_32x32x16_bf16(av1, bp, accO1, 0, 0, 0);
    }

    __syncthreads();
  }

  // epilogue
  float inv = 1.0f / lrun;
  unsigned short* orow = attn + (long)(bb * L_ + q0w + ql) * D_ + h * Dh_;
#pragma unroll
  for (int rg = 0; rg < 4; ++rg) {
    ushort4 pk;
    pk.x = f2bf(accO0[4 * rg + 0] * inv);
    pk.y = f2bf(accO0[4 * rg + 1] * inv);
    pk.z = f2bf(accO0[4 * rg + 2] * inv);
    pk.w = f2bf(accO0[4 * rg + 3] * inv);
    *reinterpret_cast<ushort4*>(orow + rg * 8 + hi * 4) = pk;
  }
#pragma unroll
  for (int rg = 0; rg < 4; ++rg) {
    ushort4 pk;
    pk.x = f2bf(accO1[4 * rg + 0] * inv);
    pk.y = f2bf(accO1[4 * rg + 1] * inv);
    pk.z = f2bf(accO1[4 * rg + 2] * inv);
    pk.w = f2bf(accO1[4 * rg + 3] * inv);
    *reinterpret_cast<ushort4*>(orow + 32 + rg * 8 + hi * 4) = pk;
  }
}

extern "C" void kernel_launch(void* const* d_in, const int* in_sizes, int n_in,
                              void* d_out, int out_size, void* d_ws, size_t ws_size,
                              hipStream_t stream) {
  const float* hs   = (const float*)d_in[0];
  const float* pe   = (const float*)d_in[1];
  const float* mask = (const float*)d_in[2];
  const float* Wq   = (const float*)d_in[3];
  const float* bq   = (const float*)d_in[4];
  const float* Wk   = (const float*)d_in[5];
  const float* bk   = (const float*)d_in[6];
  const float* Wv   = (const float*)d_in[7];
  const float* bv   = (const float*)d_in[8];
  const float* Wo   = (const float*)d_in[9];
  const float* bo   = (const float*)d_in[10];

  unsigned short* ws  = (unsigned short*)d_ws;
  unsigned short* hpe = ws;
  unsigned short* hid = hpe + 4096 * 1024;
  unsigned short* wqb = hid + 4096 * 1024;
  unsigned short* wkb = wqb + 1024 * 1024;
  unsigned short* wvb = wkb + 1024 * 1024;
  unsigned short* wob = wvb + 1024 * 1024;
  unsigned short* Qb  = wob + 1024 * 1024;
  unsigned short* Kb  = Qb + 4194304;
  unsigned short* Vb  = Kb + 4194304;     // V^T layout [BH][Dh][L]
  unsigned short* Ab  = Vb + 4194304;
  unsigned char*  mfl = (unsigned char*)(Ab + 4194304);  // 2048 flag bytes

  k_pre<<<10240, 256, 0, stream>>>(hs, pe, Wq, Wk, Wv, Wo, mask,
                                   hpe, hid, wqb, wkb, wvb, wob, mfl);

  QkvArgs qa{hpe, hpe, hid, wqb, wkb, wvb, bq, bk, bv, Qb, Kb, Vb};
  k_qkv<<<dim3(32, 8, 3), 256, 0, stream>>>(qa);

  k_attn<<<dim3(16, 32), 256, 0, stream>>>(Qb, Kb, Vb, mask, mfl, Ab);

  k_outp<<<dim3(32, 8), 256, 0, stream>>>(Ab, wob, bo, (float*)d_out);
}